// Round 1
// baseline (548.930 us; speedup 1.0000x reference)
//
#include <hip/hip_runtime.h>

// ---------------- problem constants ----------------
#define B_     8192
#define D_     32
#define H_     128
#define PH_    64
#define PREP_  10
#define CS_    8
#define CH_    32
#define NT_    16
#define NO_    4096
#define NPOST_ 4
#define TPB    32              // trajectories per block
#define DT_    0.1f
#define TWO_LOGC 1.8378770664093453f   // 2*log(sqrt(2*pi))

// ---------------- bf16 fragment-blob offsets (ushort elements) ----------------
// blob layout for a KxN weight: element ((kc*ntiles+nt)*64+lane)*8+j holds
// W[kc*32 + 4*((lane>>4)&3) + (j&3) + 16*(j>>2)][nt*16 + (lane&15)]
#define OFF_XZ   0        // 64x128   -> 8192
#define OFF_HZ   8192     // 128x128  -> 16384
#define OFF_XN   24576    // 64x128
#define OFF_HN   32768    // 128x128
#define OFF_PW1  49152    // 128x64   -> 8192
#define OFF_PW2  57344    // 64x64    -> 4096
#define OFF_WIHR 61440    // 320x128  -> 40960 each gate
#define OFF_WIHZ 102400
#define OFF_WIHN 143360
#define OFF_WHHR 184320   // 128x128 each gate
#define OFF_WHHZ 200704
#define OFF_WHHN 217088
#define BLOB_ELEMS 233472
#define INV_BYTE_OFF ((size_t)BLOB_ELEMS*2)   // 466944 bytes; inv is ushort[NT_*B_]

typedef float f4  __attribute__((ext_vector_type(4)));
typedef short bf8 __attribute__((ext_vector_type(8)));
typedef short s4v __attribute__((ext_vector_type(4)));

__device__ __forceinline__ f4 mfma16(bf8 a, bf8 b, f4 c){
  return __builtin_amdgcn_mfma_f32_16x16x32_bf16(a,b,c,0,0,0);
}
__device__ __forceinline__ unsigned short f2bf(float f){
  unsigned int u = __builtin_bit_cast(unsigned int, f);
  u = (u + 0x7FFFu + ((u>>16)&1u)) >> 16;
  return (unsigned short)u;
}
__device__ __forceinline__ f4 zf4(){ f4 z; z[0]=0.f; z[1]=0.f; z[2]=0.f; z[3]=0.f; return z; }
__device__ __forceinline__ float sigmoidf_(float x){ return 1.f/(1.f+__expf(-x)); }

// A-fragment: 8 bf16 = p[0..3] (k..k+3) and p[16..19] (k+16..k+19)
__device__ __forceinline__ bf8 lda8(const unsigned short* p){
  s4v lo = *(const s4v*)p;
  s4v hi = *(const s4v*)(p+16);
  bf8 r;
  r[0]=lo[0]; r[1]=lo[1]; r[2]=lo[2]; r[3]=lo[3];
  r[4]=hi[0]; r[5]=hi[1]; r[6]=hi[2]; r[7]=hi[3];
  return r;
}

// linear 16B-per-thread copy, n multiple of 2048 elems
__device__ __forceinline__ void stage(unsigned short* dst, const unsigned short* src, int n, int tid){
  for(int i = tid*8; i < n; i += 256*8)
    *(uint4*)(dst+i) = *(const uint4*)(src+i);
}

// 32xK @ KxN(=128) += ; wave wid owns col tiles {2w,2w+1}; acc[rowtile][coltile]
__device__ __forceinline__ void gemm128(f4 acc[2][2], const unsigned short* A, int as,
                                        const unsigned short* blob, int nkc, int lane, int wid){
  const int lc = lane & 15, lg = lane >> 4;
  const unsigned short* a0 = A + lc*as + lg*4;
  const unsigned short* a1 = a0 + 16*as;
  const unsigned short* bb = blob + ((wid*2)*64 + lane)*8;
  for(int kc=0; kc<nkc; ++kc){
    bf8 av0 = lda8(a0 + kc*32);
    bf8 av1 = lda8(a1 + kc*32);
    const unsigned short* bp = bb + kc*4096;   // kc * 8 tiles * 512
    bf8 b0 = *(const bf8*)bp;
    bf8 b1 = *(const bf8*)(bp + 512);
    acc[0][0] = mfma16(av0, b0, acc[0][0]);
    acc[1][0] = mfma16(av1, b0, acc[1][0]);
    acc[0][1] = mfma16(av0, b1, acc[0][1]);
    acc[1][1] = mfma16(av1, b1, acc[1][1]);
  }
}

// 32xK @ KxN(=64) += ; wave wid owns col tile w
__device__ __forceinline__ void gemm64(f4 acc[2], const unsigned short* A, int as,
                                       const unsigned short* blob, int nkc, int lane, int wid){
  const int lc = lane & 15, lg = lane >> 4;
  const unsigned short* a0 = A + lc*as + lg*4;
  const unsigned short* a1 = a0 + 16*as;
  const unsigned short* bb = blob + (wid*64 + lane)*8;
  for(int kc=0; kc<nkc; ++kc){
    bf8 av0 = lda8(a0 + kc*32);
    bf8 av1 = lda8(a1 + kc*32);
    bf8 b0 = *(const bf8*)(bb + kc*2048);      // kc * 4 tiles * 512
    acc[0] = mfma16(av0, b0, acc[0]);
    acc[1] = mfma16(av1, b0, acc[1]);
  }
}

// ---------------- prep kernels ----------------
__global__ void init_inv(unsigned short* inv, float* outLoss){
  int i = blockIdx.x*256 + threadIdx.x;
  if(i < NT_*B_) inv[i] = 0xFFFFu;
  if(i == 0) *outLoss = 0.f;
}

__global__ void scatter_inv(unsigned short* inv, const int* __restrict__ obs){
  int i = blockIdx.x*256 + threadIdx.x;
  if(i < NT_*NO_){
    int t = i >> 12;           // NO_ = 4096
    int o = i & 4095;
    inv[(size_t)t*B_ + obs[i]] = (unsigned short)o;
  }
}

__global__ void build_blobs(const float* __restrict__ pw1, const float* __restrict__ pw2,
                            const float* __restrict__ xzw, const float* __restrict__ hzw,
                            const float* __restrict__ xnw, const float* __restrict__ hnw,
                            const float* __restrict__ wih, const float* __restrict__ whh,
                            unsigned short* __restrict__ blob){
  int sec = blockIdx.y;
  int e = blockIdx.x*256 + threadIdx.x;
  const float* src; int Ksrc, N, ld, col0, off, cnt;
  switch(sec){
    case 0:  src=xzw; Ksrc=64;  N=128; ld=128; col0=0; off=OFF_XZ;  cnt=8192;  break;
    case 1:  src=hzw; Ksrc=128; N=128; ld=128; col0=0; off=OFF_HZ;  cnt=16384; break;
    case 2:  src=xnw; Ksrc=64;  N=128; ld=128; col0=0; off=OFF_XN;  cnt=8192;  break;
    case 3:  src=hnw; Ksrc=128; N=128; ld=128; col0=0; off=OFF_HN;  cnt=16384; break;
    case 4:  src=pw1; Ksrc=128; N=64;  ld=64;  col0=0; off=OFF_PW1; cnt=8192;  break;
    case 5:  src=pw2; Ksrc=64;  N=64;  ld=64;  col0=0; off=OFF_PW2; cnt=4096;  break;
    case 6: case 7: case 8: {
      int g = sec-6; src=wih; Ksrc=320; N=128; ld=384; col0=g*128;
      off=OFF_WIHR + g*40960; cnt=40960; } break;
    default: {
      int g = sec-9; src=whh; Ksrc=128; N=128; ld=384; col0=g*128;
      off=OFF_WHHR + g*16384; cnt=16384; } break;
  }
  if(e >= cnt) return;
  int ntiles = N >> 4;
  int perkc = ntiles << 9;
  int kc = e / perkc, rem = e % perkc;
  int nt = rem >> 9, li = rem & 511;
  int lane = li >> 3, j = li & 7;
  int n = nt*16 + (lane & 15);
  int k = kc*32 + ((lane>>4)&3)*4 + (j&3) + ((j>>2)<<4);
  float v = (k < Ksrc) ? src[(size_t)k*ld + col0 + n] : 0.f;
  blob[off + e] = f2bf(v);
}

// ---------------- fused persistent kernel ----------------
__global__ __launch_bounds__(256) void fused(
    const float* __restrict__ X, const float* __restrict__ M,
    const float* __restrict__ cov,
    const float* __restrict__ cm_w1, const float* __restrict__ cm_b1,
    const float* __restrict__ cm_w2, const float* __restrict__ cm_b2,
    const float* __restrict__ p_b1, const float* __restrict__ p_b2,
    const float* __restrict__ xz_b, const float* __restrict__ xn_b,
    const float* __restrict__ b_ih, const float* __restrict__ b_hh,
    const float* __restrict__ w_prep, const float* __restrict__ bias_prep,
    const unsigned short* __restrict__ blob, const unsigned short* __restrict__ inv,
    float* __restrict__ outH, float* __restrict__ outP, float* __restrict__ outLoss)
{
  __shared__ __align__(16) unsigned short wst[24576];          // 48KB weight stage
  __shared__ __align__(16) float          hF[TPB][H_];         // fp32 h state
  __shared__ __align__(16) unsigned short hB[TPB][H_+8];       // bf16 h
  __shared__ __align__(16) float          pF[TPB][2*D_];       // fp32 p
  __shared__ __align__(16) unsigned short pB[TPB][2*D_+8];     // bf16 p
  __shared__ __align__(16) unsigned short zhB[TPB][H_+8];      // bf16 z*h
  __shared__ __align__(16) unsigned short ginB[TPB][D_*PREP_+8]; // bf16 gru input (320)
  __shared__ __align__(16) unsigned short qB[TPB][PH_+8];      // bf16 p_model hidden
  __shared__ float wprepS[D_*4*PREP_];
  __shared__ float bprepS[D_*PREP_];
  __shared__ float bXZ[H_], bXN[H_], bP1[PH_], bP2[2*D_], bIH[3*H_], bHH[3*H_];
  __shared__ int obsO[TPB];
  __shared__ float lred[4];

  const int tid  = threadIdx.x;
  const int lane = tid & 63;
  const int wid  = tid >> 6;
  const int lc   = lane & 15, lg = lane >> 4;
  const int b0   = blockIdx.x * TPB;
  float lsum = 0.f;

  // ---- stage constants ----
  for(int i=tid;i<H_;i+=256){ bXZ[i]=xz_b[i]; bXN[i]=xn_b[i]; }
  for(int i=tid;i<PH_;i+=256) bP1[i]=p_b1[i];
  for(int i=tid;i<2*D_;i+=256) bP2[i]=p_b2[i];
  for(int i=tid;i<3*H_;i+=256){ bIH[i]=b_ih[i]; bHH[i]=b_hh[i]; }
  for(int i=tid;i<D_*4*PREP_;i+=256) wprepS[i]=w_prep[i];
  for(int i=tid;i<D_*PREP_;i+=256) bprepS[i]=bias_prep[i];

  // ---- init h = tanh(relu(cov@cm_w1+b1)@cm_w2+b2)  (scalar one-time path) ----
  {
    float* c1F = (float*)&ginB[0][0];     // [32][32] fp32 scratch aliasing ginB
    int row = tid>>3, c0 = (tid&7)*4;
    float a0=0.f,a1=0.f,a2=0.f,a3=0.f;
    #pragma unroll
    for(int k=0;k<CS_;k++){
      float cv = cov[(size_t)(b0+row)*CS_+k];
      const float* w = cm_w1 + k*CH_ + c0;
      a0 += cv*w[0]; a1 += cv*w[1]; a2 += cv*w[2]; a3 += cv*w[3];
    }
    c1F[row*CH_+c0+0]=fmaxf(a0+cm_b1[c0+0],0.f);
    c1F[row*CH_+c0+1]=fmaxf(a1+cm_b1[c0+1],0.f);
    c1F[row*CH_+c0+2]=fmaxf(a2+cm_b1[c0+2],0.f);
    c1F[row*CH_+c0+3]=fmaxf(a3+cm_b1[c0+3],0.f);
    __syncthreads();
    int hc0 = (tid&7)*16;
    for(int c=hc0;c<hc0+16;c++){
      float a = cm_b2[c];
      for(int k=0;k<CH_;k++) a += c1F[row*CH_+k]*cm_w2[k*H_+c];
      float hv = tanhf(a);
      hF[row][c]=hv; hB[row][c]=f2bf(hv);
    }
  }

  f4 zreg[2][2], rr[2][2], zj[2][2];

  // ---- p_model: q=relu(h@pw1+b1); p=q@pw2+b2 ----
  auto pmodel = [&](){
    __syncthreads();
    stage(wst,      blob+OFF_PW1, 8192, tid);
    stage(wst+8192, blob+OFF_PW2, 4096, tid);
    __syncthreads();
    f4 q[2]; q[0]=zf4(); q[1]=zf4();
    gemm64(q, &hB[0][0], H_+8, wst, 4, lane, wid);
    int c = wid*16 + lc;
    #pragma unroll
    for(int rt=0;rt<2;rt++)
      #pragma unroll
      for(int g=0;g<4;g++){
        int r = rt*16 + lg*4 + g;
        qB[r][c] = f2bf(fmaxf(q[rt][g]+bP1[c], 0.f));
      }
    __syncthreads();
    f4 p[2]; p[0]=zf4(); p[1]=zf4();
    gemm64(p, &qB[0][0], PH_+8, wst+8192, 2, lane, wid);
    #pragma unroll
    for(int rt=0;rt<2;rt++)
      #pragma unroll
      for(int g=0;g<4;g++){
        int r = rt*16 + lg*4 + g;
        float pv = p[rt][g] + bP2[c];
        pF[r][c] = pv; pB[r][c] = f2bf(pv);
      }
  };

  // ---- euler: h += DT*(1-z)*(n-h) ----
  auto euler = [&](){
    __syncthreads();
    stage(wst,      blob+OFF_XZ, 8192,  tid);
    stage(wst+8192, blob+OFF_HZ, 16384, tid);
    __syncthreads();
    f4 a[2][2]; a[0][0]=zf4(); a[0][1]=zf4(); a[1][0]=zf4(); a[1][1]=zf4();
    gemm128(a, &pB[0][0], 2*D_+8, wst,      2, lane, wid);
    gemm128(a, &hB[0][0], H_+8,   wst+8192, 4, lane, wid);
    #pragma unroll
    for(int rt=0;rt<2;rt++)
      #pragma unroll
      for(int ct=0;ct<2;ct++)
        #pragma unroll
        for(int g=0;g<4;g++){
          int r = rt*16+lg*4+g, c = (wid*2+ct)*16+lc;
          float zz = sigmoidf_(a[rt][ct][g] + bXZ[c]);
          zreg[rt][ct][g] = zz;
          zhB[r][c] = f2bf(zz * hF[r][c]);
        }
    __syncthreads();
    stage(wst,      blob+OFF_XN, 8192,  tid);
    stage(wst+8192, blob+OFF_HN, 16384, tid);
    __syncthreads();
    f4 n[2][2]; n[0][0]=zf4(); n[0][1]=zf4(); n[1][0]=zf4(); n[1][1]=zf4();
    gemm128(n, &pB[0][0],  2*D_+8, wst,      2, lane, wid);
    gemm128(n, &zhB[0][0], H_+8,   wst+8192, 4, lane, wid);
    #pragma unroll
    for(int rt=0;rt<2;rt++)
      #pragma unroll
      for(int ct=0;ct<2;ct++)
        #pragma unroll
        for(int g=0;g<4;g++){
          int r = rt*16+lg*4+g, c = (wid*2+ct)*16+lc;
          float nn = tanhf(n[rt][ct][g] + bXN[c]);
          float ho = hF[r][c];
          float zz = zreg[rt][ct][g];
          float hv = ho + DT_*(1.f-zz)*(nn-ho);
          hF[r][c] = hv; hB[r][c] = f2bf(hv);
        }
  };

  // ---- jump at observation time t ----
  auto jump = [&](int t){
    __syncthreads();
    if(tid < TPB){
      unsigned short v = inv[(size_t)t*B_ + b0 + tid];
      obsO[tid] = (v == 0xFFFFu) ? -1 : (int)v;
    }
    __syncthreads();
    { // loss + gin (masked; unobserved rows get gin=0, loss=0)
      int row = tid>>3, d0 = (tid&7)*4;
      int o = obsO[row];
      float xa[4] = {0.f,0.f,0.f,0.f}, ma[4] = {0.f,0.f,0.f,0.f};
      if(o >= 0){
        const float4 xv = *(const float4*)(X + ((size_t)t*NO_ + o)*D_ + d0);
        const float4 mv = *(const float4*)(M + ((size_t)t*NO_ + o)*D_ + d0);
        xa[0]=xv.x; xa[1]=xv.y; xa[2]=xv.z; xa[3]=xv.w;
        ma[0]=mv.x; ma[1]=mv.y; ma[2]=mv.z; ma[3]=mv.w;
      }
      #pragma unroll
      for(int j=0;j<4;j++){
        int d = d0 + j;
        float mean = pF[row][d], lv = pF[row][D_+d];
        float sg = __expf(0.5f*lv);
        float er = (xa[j]-mean)/sg;
        lsum += 0.5f*((er*er + lv + TWO_LOGC)*ma[j]);
        const float* wp = wprepS + d*4*PREP_;
        #pragma unroll
        for(int pr=0;pr<PREP_;pr++){
          float s = xa[j]*wp[pr] + mean*wp[PREP_+pr] + lv*wp[2*PREP_+pr] + er*wp[3*PREP_+pr];
          s = fmaxf(s + bprepS[d*PREP_+pr], 0.f) * ma[j];
          ginB[row][d*PREP_+pr] = f2bf(s);
        }
      }
    }
    // ---- r gate ----
    f4 a[2][2]; a[0][0]=zf4(); a[0][1]=zf4(); a[1][0]=zf4(); a[1][1]=zf4();
    __syncthreads();
    stage(wst, blob+OFF_WIHR, 20480, tid); __syncthreads();
    gemm128(a, &ginB[0][0],   D_*PREP_+8, wst, 5, lane, wid);
    __syncthreads(); stage(wst, blob+OFF_WIHR+20480, 20480, tid); __syncthreads();
    gemm128(a, &ginB[0][160], D_*PREP_+8, wst, 5, lane, wid);
    __syncthreads(); stage(wst, blob+OFF_WHHR, 16384, tid); __syncthreads();
    gemm128(a, &hB[0][0], H_+8, wst, 4, lane, wid);
    #pragma unroll
    for(int rt=0;rt<2;rt++)
      #pragma unroll
      for(int ct=0;ct<2;ct++)
        #pragma unroll
        for(int g=0;g<4;g++){
          int c = (wid*2+ct)*16+lc;
          rr[rt][ct][g] = sigmoidf_(a[rt][ct][g] + bIH[c] + bHH[c]);
        }
    // ---- z gate ----
    a[0][0]=zf4(); a[0][1]=zf4(); a[1][0]=zf4(); a[1][1]=zf4();
    __syncthreads(); stage(wst, blob+OFF_WIHZ, 20480, tid); __syncthreads();
    gemm128(a, &ginB[0][0],   D_*PREP_+8, wst, 5, lane, wid);
    __syncthreads(); stage(wst, blob+OFF_WIHZ+20480, 20480, tid); __syncthreads();
    gemm128(a, &ginB[0][160], D_*PREP_+8, wst, 5, lane, wid);
    __syncthreads(); stage(wst, blob+OFF_WHHZ, 16384, tid); __syncthreads();
    gemm128(a, &hB[0][0], H_+8, wst, 4, lane, wid);
    #pragma unroll
    for(int rt=0;rt<2;rt++)
      #pragma unroll
      for(int ct=0;ct<2;ct++)
        #pragma unroll
        for(int g=0;g<4;g++){
          int c = (wid*2+ct)*16+lc;
          zj[rt][ct][g] = sigmoidf_(a[rt][ct][g] + bIH[H_+c] + bHH[H_+c]);
        }
    // ---- n gate (gi and gh kept separate: n = tanh(gi + r*gh)) ----
    f4 gi[2][2], gh[2][2];
    gi[0][0]=zf4(); gi[0][1]=zf4(); gi[1][0]=zf4(); gi[1][1]=zf4();
    gh[0][0]=zf4(); gh[0][1]=zf4(); gh[1][0]=zf4(); gh[1][1]=zf4();
    __syncthreads(); stage(wst, blob+OFF_WIHN, 20480, tid); __syncthreads();
    gemm128(gi, &ginB[0][0],   D_*PREP_+8, wst, 5, lane, wid);
    __syncthreads(); stage(wst, blob+OFF_WIHN+20480, 20480, tid); __syncthreads();
    gemm128(gi, &ginB[0][160], D_*PREP_+8, wst, 5, lane, wid);
    __syncthreads(); stage(wst, blob+OFF_WHHN, 16384, tid); __syncthreads();
    gemm128(gh, &hB[0][0], H_+8, wst, 4, lane, wid);
    __syncthreads();   // all hB reads done before conditional h writes below
    #pragma unroll
    for(int rt=0;rt<2;rt++)
      #pragma unroll
      for(int ct=0;ct<2;ct++)
        #pragma unroll
        for(int g=0;g<4;g++){
          int r = rt*16+lg*4+g, c = (wid*2+ct)*16+lc;
          float giv = gi[rt][ct][g] + bIH[2*H_+c];
          float ghv = gh[rt][ct][g] + bHH[2*H_+c];
          float nn = tanhf(giv + rr[rt][ct][g]*ghv);
          float zz = zj[rt][ct][g];
          float hv = (1.f-zz)*nn + zz*hF[r][c];
          if(obsO[r] >= 0){ hF[r][c] = hv; hB[r][c] = f2bf(hv); }
        }
  };

  // ---- sequence ----
  pmodel();
  for(int t=0;t<NT_;t++){
    euler();
    pmodel();
    jump(t);
    pmodel();
  }
  for(int it=0;it<NPOST_;it++){
    euler();
    pmodel();
  }

  // ---- outputs ----
  __syncthreads();
  {
    int row = tid>>3, c0 = (tid&7)*16;
    #pragma unroll
    for(int j=0;j<16;j+=4)
      *(float4*)(outH + (size_t)(b0+row)*H_ + c0 + j) = *(const float4*)&hF[row][c0+j];
    int pc0 = (tid&7)*8;
    #pragma unroll
    for(int j=0;j<8;j+=4)
      *(float4*)(outP + (size_t)(b0+row)*2*D_ + pc0 + j) = *(const float4*)&pF[row][pc0+j];
  }
  // loss reduce
  #pragma unroll
  for(int off=32;off>0;off>>=1) lsum += __shfl_down(lsum, off);
  if(lane==0) lred[wid]=lsum;
  __syncthreads();
  if(tid==0) atomicAdd(outLoss, lred[0]+lred[1]+lred[2]+lred[3]);
}

// ---------------- launcher ----------------
extern "C" void kernel_launch(void* const* d_in, const int* in_sizes, int n_in,
                              void* d_out, int out_size, void* d_ws, size_t ws_size,
                              hipStream_t stream){
  const float* X      = (const float*)d_in[0];
  const float* M      = (const float*)d_in[1];
  const int*   obs    = (const int*)  d_in[2];
  const float* cov    = (const float*)d_in[3];
  const float* cm_w1  = (const float*)d_in[4];
  const float* cm_b1  = (const float*)d_in[5];
  const float* cm_w2  = (const float*)d_in[6];
  const float* cm_b2  = (const float*)d_in[7];
  const float* p_w1   = (const float*)d_in[8];
  const float* p_b1   = (const float*)d_in[9];
  const float* p_w2   = (const float*)d_in[10];
  const float* p_b2   = (const float*)d_in[11];
  const float* xz_w   = (const float*)d_in[12];
  const float* xz_b   = (const float*)d_in[13];
  const float* hz_w   = (const float*)d_in[14];
  const float* xn_w   = (const float*)d_in[15];
  const float* xn_b   = (const float*)d_in[16];
  const float* hn_w   = (const float*)d_in[17];
  const float* w_ih   = (const float*)d_in[18];
  const float* w_hh   = (const float*)d_in[19];
  const float* b_ih   = (const float*)d_in[20];
  const float* b_hh   = (const float*)d_in[21];
  const float* w_prep = (const float*)d_in[22];
  const float* bprep  = (const float*)d_in[23];

  unsigned short* blob = (unsigned short*)d_ws;                       // 466944 B
  unsigned short* inv  = (unsigned short*)((char*)d_ws + INV_BYTE_OFF); // +262144 B (total ~712KB)
  float* outH = (float*)d_out;
  float* outP = outH + (size_t)B_*H_;
  float* outLoss = outP + (size_t)B_*2*D_;

  init_inv   <<<dim3((NT_*B_+255)/256), dim3(256), 0, stream>>>(inv, outLoss);
  scatter_inv<<<dim3((NT_*NO_+255)/256), dim3(256), 0, stream>>>(inv, obs);
  build_blobs<<<dim3(160,12), dim3(256), 0, stream>>>(p_w1,p_w2,xz_w,hz_w,xn_w,hn_w,w_ih,w_hh, blob);
  fused      <<<dim3(B_/TPB), dim3(256), 0, stream>>>(
      X, M, cov, cm_w1, cm_b1, cm_w2, cm_b2, p_b1, p_b2, xz_b, xn_b,
      b_ih, b_hh, w_prep, bprep, blob, inv, outH, outP, outLoss);
}